// Round 10
// baseline (274.949 us; speedup 1.0000x reference)
//
#include <hip/hip_runtime.h>
#include <hip/hip_fp16.h>

#define NN   100000
#define E0   1600000
#define ET   1700000
#define NEG  0.2f
#define EPSV 1e-16f
#define NB   391            // dst buckets of 256 node ids
#define BS   1024
#define NBLK ((ET + BS - 1) / BS)   // 1661
#define GEMM_BLK 1024

// ---- bucket counts: LDS-aggregated histogram over 391 dst buckets ----
__global__ __launch_bounds__(BS) void k_bcount(const int* __restrict__ ei, int* __restrict__ bcnt)
{
    __shared__ int cnt[NB];
    int t = threadIdx.x;
    if (t < NB) cnt[t] = 0;
    __syncthreads();
    int idx = blockIdx.x * BS + t;
    if (idx < ET) {
        int d = (idx < E0) ? ei[E0 + idx] : (idx - E0);
        atomicAdd(&cnt[d >> 8], 1);
    }
    __syncthreads();
    if (t < NB && cnt[t]) atomicAdd(&bcnt[t], cnt[t]);
}

// ---- exclusive scan of 391 bucket counts -> bbase, bcursor; rowptr sentinel ----
__global__ __launch_bounds__(512) void k_bscan(const int* __restrict__ bcnt,
                                               int* __restrict__ bbase, int* __restrict__ bcursor,
                                               int* __restrict__ rowptr)
{
    int t = threadIdx.x;
    int v = (t < NB) ? bcnt[t] : 0;
    int lane = t & 63, wid = t >> 6;
    int sc = v;
#pragma unroll
    for (int off = 1; off < 64; off <<= 1) {
        int u = __shfl_up(sc, off, 64);
        if (lane >= off) sc += u;
    }
    __shared__ int wsum[8];
    if (lane == 63) wsum[wid] = sc;
    __syncthreads();
    int woff = 0;
    for (int k = 0; k < wid; ++k) woff += wsum[k];
    if (t < NB) { int e = sc + woff - v; bbase[t] = e; bcursor[t] = e; }
    if (t == 0) rowptr[NN] = ET;
}

// ---- bin edges by dst bucket; packed record = s | (d&255)<<17 (s < 2^17) ----
__global__ __launch_bounds__(BS) void k_bscat(const int* __restrict__ ei,
                                              int* __restrict__ bcursor, int* __restrict__ bin)
{
    __shared__ int cnt[NB];
    __shared__ int base[NB];
    int t = threadIdx.x;
    if (t < NB) cnt[t] = 0;
    __syncthreads();
    int idx = blockIdx.x * BS + t;
    int b = 0, r = 0, pk = 0;
    if (idx < ET) {
        int s, d;
        if (idx < E0) { s = ei[idx]; d = ei[E0 + idx]; } else { s = d = idx - E0; }
        b = d >> 8;
        pk = s | ((d & 255) << 17);
        r = atomicAdd(&cnt[b], 1);
    }
    __syncthreads();
    if (t < NB && cnt[t]) base[t] = atomicAdd(&bcursor[t], cnt[t]);
    __syncthreads();
    if (idx < ET) bin[base[b] + r] = pk;
}

// ---- per-bucket CSR: local deg hist, local scan -> rowptr, local scatter -> csr ----
__global__ __launch_bounds__(256) void k_bcsr(const int* __restrict__ bin,
                                              const int* __restrict__ bbase, const int* __restrict__ bcnt,
                                              int* __restrict__ rowptr, int* __restrict__ csr)
{
    int b = blockIdx.x;
    int beg = bbase[b], cntB = bcnt[b];
    int t = threadIdx.x;
    __shared__ int deg[256];
    __shared__ int cur[256];
    deg[t] = 0;
    __syncthreads();
    for (int i = t; i < cntB; i += 256) atomicAdd(&deg[bin[beg + i] >> 17], 1);
    __syncthreads();
    int v = deg[t];
    int lane = t & 63, wid = t >> 6;
    int sc = v;
#pragma unroll
    for (int off = 1; off < 64; off <<= 1) {
        int u = __shfl_up(sc, off, 64);
        if (lane >= off) sc += u;
    }
    __shared__ int wsum[4];
    if (lane == 63) wsum[wid] = sc;
    __syncthreads();
    int woff = 0;
    for (int k = 0; k < wid; ++k) woff += wsum[k];
    int excl = sc - v + woff;
    cur[t] = excl;
    int node = (b << 8) + t;
    if (node < NN) rowptr[node] = beg + excl;
    __syncthreads();
    for (int i = t; i < cntB; i += 256) {
        int e = bin[beg + i];
        int r = atomicAdd(&cur[e >> 17], 1);
        csr[beg + r] = e & 0x1FFFF;
    }
}

// ---- Layer 1 GEMM: W1 column pinned in VGPRs via asm (compiler otherwise
// sinks the loads back into the loop: R9 showed VGPR=44 / 56us regardless of
// launch_bounds). 4 independent accumulators for ILP. ----
__global__ __launch_bounds__(256, 4) void k_gemm1(
    const float* __restrict__ x, const float* __restrict__ W1,
    const float* __restrict__ as1, const float* __restrict__ ad1,
    __half* __restrict__ h1h, float* __restrict__ asrc1, float* __restrict__ adst1)
{
    int lane = threadIdx.x & 63;
    float wcol[64];
#pragma unroll
    for (int k = 0; k < 64; ++k) wcol[k] = W1[k * 64 + lane];
    // Force all 64 values to be materialized and kept in VGPRs.
#pragma unroll
    for (int k = 0; k < 64; ++k) asm volatile("" : "+v"(wcol[k]));
    float attS = as1[lane], attD = ad1[lane];
    int wid = (blockIdx.x * 256 + threadIdx.x) >> 6;
    const int nw = GEMM_BLK * 4;
    for (int n0 = wid; n0 < NN; n0 += nw) {
        int n = __builtin_amdgcn_readfirstlane(n0);
        const float4* xr = (const float4*)(x + (size_t)n * 64);
        float acc0 = 0.f, acc1 = 0.f, acc2 = 0.f, acc3 = 0.f;
#pragma unroll
        for (int m = 0; m < 16; m += 4) {
            float4 x0 = xr[m], x1 = xr[m + 1], x2 = xr[m + 2], x3 = xr[m + 3];
            acc0 += x0.x * wcol[4*m+0]  + x0.y * wcol[4*m+1]
                  + x0.z * wcol[4*m+2]  + x0.w * wcol[4*m+3];
            acc1 += x1.x * wcol[4*m+4]  + x1.y * wcol[4*m+5]
                  + x1.z * wcol[4*m+6]  + x1.w * wcol[4*m+7];
            acc2 += x2.x * wcol[4*m+8]  + x2.y * wcol[4*m+9]
                  + x2.z * wcol[4*m+10] + x2.w * wcol[4*m+11];
            acc3 += x3.x * wcol[4*m+12] + x3.y * wcol[4*m+13]
                  + x3.z * wcol[4*m+14] + x3.w * wcol[4*m+15];
        }
        float acc = (acc0 + acc1) + (acc2 + acc3);
        h1h[(size_t)n * 64 + lane] = __float2half(acc);
        float av = acc * attS, dv = acc * attD;
#pragma unroll
        for (int off = 8; off; off >>= 1) {
            av += __shfl_down(av, off, 16);
            dv += __shfl_down(dv, off, 16);
        }
        if ((lane & 15) == 0) {
            asrc1[n * 4 + (lane >> 4)] = av;
            adst1[n * 4 + (lane >> 4)] = dv;
        }
    }
}

// ---- Layer 1 aggregation: 4 LANES PER NODE (lane = head). Each lane owns
// its head's 16 channels (16 fp32 accs), loads 32B of each gathered h1 row,
// own exp/denominator. Epilogue in-register; 2-step shfl_xor combine. ----
__global__ __launch_bounds__(256) void k_e1agg(
    const int* __restrict__ rowptr, const int* __restrict__ csr,
    const float* __restrict__ asrc1, const float* __restrict__ adst1,
    const __half* __restrict__ h1h, const float* __restrict__ b1,
    const float* __restrict__ W2, float* __restrict__ g)
{
    int t = threadIdx.x;
    int hh = t & 3;                 // head
    int n = blockIdx.x * 64 + (t >> 2);
    if (n >= NN) return;
    float ad = adst1[n * 4 + hh];
    int beg = rowptr[n], end = rowptr[n + 1];
    float acc[16];
#pragma unroll
    for (int c = 0; c < 16; ++c) acc[c] = 0.f;
    float den = 0.f;
    for (int j = beg; j < end; ++j) {
        int s = csr[j];
        float as = asrc1[s * 4 + hh];
        float a = as + ad; a = a > 0.f ? a : NEG * a;
        float ev = __expf(a);
        den += ev;
        const uint4* hp = (const uint4*)(h1h + (size_t)s * 64 + hh * 16);
        uint4 r0 = hp[0], r1 = hp[1];
#define U4ACC(r, base) { \
        float2 f0 = __half22float2(*(const __half2*)&r.x); \
        float2 f1 = __half22float2(*(const __half2*)&r.y); \
        float2 f2 = __half22float2(*(const __half2*)&r.z); \
        float2 f3 = __half22float2(*(const __half2*)&r.w); \
        acc[base+0] += ev * f0.x; acc[base+1] += ev * f0.y; \
        acc[base+2] += ev * f1.x; acc[base+3] += ev * f1.y; \
        acc[base+4] += ev * f2.x; acc[base+5] += ev * f2.y; \
        acc[base+6] += ev * f3.x; acc[base+7] += ev * f3.y; }
        U4ACC(r0, 0) U4ACC(r1, 8)
#undef U4ACC
    }
    float inv = 1.f / (den + EPSV);
    const float4* bp = (const float4*)(b1 + hh * 16);
    const float4* wp = (const float4*)(W2 + hh * 16);
    float gv = 0.f;
#pragma unroll
    for (int q = 0; q < 4; ++q) {
        float4 bb = bp[q], w2 = wp[q];
        float v0 = acc[4*q+0] * inv + bb.x; v0 = v0 > 0.f ? v0 : __expf(v0) - 1.f;
        float v1 = acc[4*q+1] * inv + bb.y; v1 = v1 > 0.f ? v1 : __expf(v1) - 1.f;
        float v2 = acc[4*q+2] * inv + bb.z; v2 = v2 > 0.f ? v2 : __expf(v2) - 1.f;
        float v3 = acc[4*q+3] * inv + bb.w; v3 = v3 > 0.f ? v3 : __expf(v3) - 1.f;
        gv += v0 * w2.x + v1 * w2.y + v2 * w2.z + v3 * w2.w;
    }
    gv += __shfl_xor(gv, 1);
    gv += __shfl_xor(gv, 2);
    if (hh == 0) g[n] = gv;
}

// ---- Layer 2 aggregation: 16 lanes per node, 16 edges in parallel ----
__global__ __launch_bounds__(256) void k_e2agg(
    const int* __restrict__ rowptr, const int* __restrict__ csr,
    const float* __restrict__ g, const float* __restrict__ att_s2,
    const float* __restrict__ att_d2, const float* __restrict__ b2,
    float* __restrict__ out)
{
    int t = threadIdx.x;
    int grp = t >> 4, cc = t & 15;
    int n = blockIdx.x * 16 + grp;     // NN/16 = 6250 exact
    float cs = att_s2[0];
    float gdcd = g[n] * att_d2[0];
    int beg = rowptr[n], end = rowptr[n + 1];
    float acc = 0.f, den = 0.f;
    for (int j = beg + cc; j < end; j += 16) {
        float gz = g[csr[j]];
        float a = gz * cs + gdcd;
        a = a > 0.f ? a : NEG * a;
        float ev = __expf(a);
        den += ev;
        acc += ev * gz;
    }
#pragma unroll
    for (int m = 1; m <= 8; m <<= 1) {
        acc += __shfl_xor(acc, m);
        den += __shfl_xor(den, m);
    }
    if (cc == 0) out[n] = acc / (den + EPSV) + b2[0];
}

extern "C" void kernel_launch(void* const* d_in, const int* in_sizes, int n_in,
                              void* d_out, int out_size, void* d_ws, size_t ws_size,
                              hipStream_t stream)
{
    const float* x   = (const float*)d_in[0];
    const int*   ei  = (const int*)d_in[1];
    const float* W1  = (const float*)d_in[2];
    const float* as1 = (const float*)d_in[3];
    const float* ad1 = (const float*)d_in[4];
    const float* b1  = (const float*)d_in[5];
    const float* W2  = (const float*)d_in[6];
    const float* as2 = (const float*)d_in[7];
    const float* ad2 = (const float*)d_in[8];
    const float* b2  = (const float*)d_in[9];
    float* out = (float*)d_out;

    // workspace layout (4-byte units, 128-slot aligned blocks)
    int*   iw      = (int*)d_ws;
    float* fw      = (float*)d_ws;
    int*   bcnt    = iw;                  //      391
    int*   bbase   = iw + 512;            //      391
    int*   bcursor = iw + 1024;           //      391
    int*   rowptr  = iw + 1536;           //  100,001
    int*   bin     = iw + 101632;         // 1,700,000
    int*   csr     = iw + 1801728;        // 1,700,000
    float* adst1   = fw + 3501824;        //   400,000
    float* asrc1   = fw + 3901952;        //   400,000
    float* g       = fw + 4302080;        //   100,000
    __half* h1h    = (__half*)(fw + 4402176); // 6.4M halves
    // total ≈ 7.6M slots ≈ 30.4 MB

    hipMemsetAsync(bcnt, 0, NB * sizeof(int), stream);

    k_bcount<<<NBLK, BS, 0, stream>>>(ei, bcnt);
    k_bscan <<<1, 512, 0, stream>>>(bcnt, bbase, bcursor, rowptr);
    k_bscat <<<NBLK, BS, 0, stream>>>(ei, bcursor, bin);
    k_bcsr  <<<NB, 256, 0, stream>>>(bin, bbase, bcnt, rowptr, csr);
    k_gemm1 <<<GEMM_BLK, 256, 0, stream>>>(x, W1, as1, ad1, h1h, asrc1, adst1);
    k_e1agg <<<(NN * 4 + 255) / 256, 256, 0, stream>>>(rowptr, csr, asrc1, adst1, h1h, b1, W2, g);
    k_e2agg <<<NN / 16, 256, 0, stream>>>(rowptr, csr, g, as2, ad2, b2, out);
}

// Round 11
// 270.927 us; speedup vs baseline: 1.0148x; 1.0148x over previous
//
#include <hip/hip_runtime.h>
#include <hip/hip_fp16.h>

#define NN   100000
#define E0   1600000
#define ET   1700000
#define NEG  0.2f
#define EPSV 1e-16f
#define NB   391            // dst buckets of 256 node ids
#define BS   1024
#define NBLK ((ET + BS - 1) / BS)   // 1661
#define GEMM_BLK 1024

// ---- bucket counts: LDS-aggregated histogram over 391 dst buckets ----
__global__ __launch_bounds__(BS) void k_bcount(const int* __restrict__ ei, int* __restrict__ bcnt)
{
    __shared__ int cnt[NB];
    int t = threadIdx.x;
    if (t < NB) cnt[t] = 0;
    __syncthreads();
    int idx = blockIdx.x * BS + t;
    if (idx < ET) {
        int d = (idx < E0) ? ei[E0 + idx] : (idx - E0);
        atomicAdd(&cnt[d >> 8], 1);
    }
    __syncthreads();
    if (t < NB && cnt[t]) atomicAdd(&bcnt[t], cnt[t]);
}

// ---- exclusive scan of 391 bucket counts -> bbase, bcursor; rowptr sentinel ----
__global__ __launch_bounds__(512) void k_bscan(const int* __restrict__ bcnt,
                                               int* __restrict__ bbase, int* __restrict__ bcursor,
                                               int* __restrict__ rowptr)
{
    int t = threadIdx.x;
    int v = (t < NB) ? bcnt[t] : 0;
    int lane = t & 63, wid = t >> 6;
    int sc = v;
#pragma unroll
    for (int off = 1; off < 64; off <<= 1) {
        int u = __shfl_up(sc, off, 64);
        if (lane >= off) sc += u;
    }
    __shared__ int wsum[8];
    if (lane == 63) wsum[wid] = sc;
    __syncthreads();
    int woff = 0;
    for (int k = 0; k < wid; ++k) woff += wsum[k];
    if (t < NB) { int e = sc + woff - v; bbase[t] = e; bcursor[t] = e; }
    if (t == 0) rowptr[NN] = ET;
}

// ---- bin edges by dst bucket; packed record = s | (d&255)<<17 (s < 2^17) ----
__global__ __launch_bounds__(BS) void k_bscat(const int* __restrict__ ei,
                                              int* __restrict__ bcursor, int* __restrict__ bin)
{
    __shared__ int cnt[NB];
    __shared__ int base[NB];
    int t = threadIdx.x;
    if (t < NB) cnt[t] = 0;
    __syncthreads();
    int idx = blockIdx.x * BS + t;
    int b = 0, r = 0, pk = 0;
    if (idx < ET) {
        int s, d;
        if (idx < E0) { s = ei[idx]; d = ei[E0 + idx]; } else { s = d = idx - E0; }
        b = d >> 8;
        pk = s | ((d & 255) << 17);
        r = atomicAdd(&cnt[b], 1);
    }
    __syncthreads();
    if (t < NB && cnt[t]) base[t] = atomicAdd(&bcursor[t], cnt[t]);
    __syncthreads();
    if (idx < ET) bin[base[b] + r] = pk;
}

// ---- per-bucket CSR: local deg hist, local scan -> rowptr, local scatter -> csr ----
__global__ __launch_bounds__(256) void k_bcsr(const int* __restrict__ bin,
                                              const int* __restrict__ bbase, const int* __restrict__ bcnt,
                                              int* __restrict__ rowptr, int* __restrict__ csr)
{
    int b = blockIdx.x;
    int beg = bbase[b], cntB = bcnt[b];
    int t = threadIdx.x;
    __shared__ int deg[256];
    __shared__ int cur[256];
    deg[t] = 0;
    __syncthreads();
    for (int i = t; i < cntB; i += 256) atomicAdd(&deg[bin[beg + i] >> 17], 1);
    __syncthreads();
    int v = deg[t];
    int lane = t & 63, wid = t >> 6;
    int sc = v;
#pragma unroll
    for (int off = 1; off < 64; off <<= 1) {
        int u = __shfl_up(sc, off, 64);
        if (lane >= off) sc += u;
    }
    __shared__ int wsum[4];
    if (lane == 63) wsum[wid] = sc;
    __syncthreads();
    int woff = 0;
    for (int k = 0; k < wid; ++k) woff += wsum[k];
    int excl = sc - v + woff;
    cur[t] = excl;
    int node = (b << 8) + t;
    if (node < NN) rowptr[node] = beg + excl;
    __syncthreads();
    for (int i = t; i < cntB; i += 256) {
        int e = bin[beg + i];
        int r = atomicAdd(&cur[e >> 17], 1);
        csr[beg + r] = e & 0x1FFFF;
    }
}

// ---- Layer 1 GEMM: PERSISTENT grid. W1 staged to LDS ONCE per block
// (R6 re-staged it 25k times = 400MB L2 traffic; R7-R10's register-array
// version was defeated by the allocator, VGPR stuck at 44 with scratch
// reloads). Inner loop: uniform x loads (scalar path) + conflict-free
// ds_read_b32 of W + v_fmac. ----
__global__ __launch_bounds__(256, 4) void k_gemm1(
    const float* __restrict__ x, const float* __restrict__ W1,
    const float* __restrict__ as1, const float* __restrict__ ad1,
    __half* __restrict__ h1h, float* __restrict__ asrc1, float* __restrict__ adst1)
{
    __shared__ float Wl[4096];
    int tid = threadIdx.x;
    for (int i = tid; i < 4096; i += 256) Wl[i] = W1[i];
    __syncthreads();
    int lane = tid & 63, w = tid >> 6;
    float attS = as1[lane], attD = ad1[lane];
    for (int n0 = blockIdx.x * 4 + w; n0 < NN; n0 += GEMM_BLK * 4) {
        int n = __builtin_amdgcn_readfirstlane(n0);
        const float4* xr = (const float4*)(x + (size_t)n * 64);
        float acc0 = 0.f, acc1 = 0.f, acc2 = 0.f, acc3 = 0.f;
#pragma unroll
        for (int m = 0; m < 16; m += 4) {
            float4 x0 = xr[m], x1 = xr[m + 1], x2 = xr[m + 2], x3 = xr[m + 3];
            acc0 += x0.x * Wl[(4*m+ 0)*64+lane] + x0.y * Wl[(4*m+ 1)*64+lane]
                  + x0.z * Wl[(4*m+ 2)*64+lane] + x0.w * Wl[(4*m+ 3)*64+lane];
            acc1 += x1.x * Wl[(4*m+ 4)*64+lane] + x1.y * Wl[(4*m+ 5)*64+lane]
                  + x1.z * Wl[(4*m+ 6)*64+lane] + x1.w * Wl[(4*m+ 7)*64+lane];
            acc2 += x2.x * Wl[(4*m+ 8)*64+lane] + x2.y * Wl[(4*m+ 9)*64+lane]
                  + x2.z * Wl[(4*m+10)*64+lane] + x2.w * Wl[(4*m+11)*64+lane];
            acc3 += x3.x * Wl[(4*m+12)*64+lane] + x3.y * Wl[(4*m+13)*64+lane]
                  + x3.z * Wl[(4*m+14)*64+lane] + x3.w * Wl[(4*m+15)*64+lane];
        }
        float acc = (acc0 + acc1) + (acc2 + acc3);
        h1h[(size_t)n * 64 + lane] = __float2half(acc);
        float av = acc * attS, dv = acc * attD;
#pragma unroll
        for (int off = 8; off; off >>= 1) {
            av += __shfl_down(av, off, 16);
            dv += __shfl_down(dv, off, 16);
        }
        if ((lane & 15) == 0) {
            asrc1[n * 4 + (lane >> 4)] = av;
            adst1[n * 4 + (lane >> 4)] = dv;
        }
    }
}

// ---- Layer 1 aggregation: 4 LANES PER NODE (lane = head). Each lane owns
// its head's 16 channels (16 fp32 accs), loads 32B of each gathered h1 row,
// own exp/denominator. Epilogue in-register; 2-step shfl_xor combine. ----
__global__ __launch_bounds__(256) void k_e1agg(
    const int* __restrict__ rowptr, const int* __restrict__ csr,
    const float* __restrict__ asrc1, const float* __restrict__ adst1,
    const __half* __restrict__ h1h, const float* __restrict__ b1,
    const float* __restrict__ W2, float* __restrict__ g)
{
    int t = threadIdx.x;
    int hh = t & 3;                 // head
    int n = blockIdx.x * 64 + (t >> 2);
    if (n >= NN) return;
    float ad = adst1[n * 4 + hh];
    int beg = rowptr[n], end = rowptr[n + 1];
    float acc[16];
#pragma unroll
    for (int c = 0; c < 16; ++c) acc[c] = 0.f;
    float den = 0.f;
    for (int j = beg; j < end; ++j) {
        int s = csr[j];
        float as = asrc1[s * 4 + hh];
        float a = as + ad; a = a > 0.f ? a : NEG * a;
        float ev = __expf(a);
        den += ev;
        const uint4* hp = (const uint4*)(h1h + (size_t)s * 64 + hh * 16);
        uint4 r0 = hp[0], r1 = hp[1];
#define U4ACC(r, base) { \
        float2 f0 = __half22float2(*(const __half2*)&r.x); \
        float2 f1 = __half22float2(*(const __half2*)&r.y); \
        float2 f2 = __half22float2(*(const __half2*)&r.z); \
        float2 f3 = __half22float2(*(const __half2*)&r.w); \
        acc[base+0] += ev * f0.x; acc[base+1] += ev * f0.y; \
        acc[base+2] += ev * f1.x; acc[base+3] += ev * f1.y; \
        acc[base+4] += ev * f2.x; acc[base+5] += ev * f2.y; \
        acc[base+6] += ev * f3.x; acc[base+7] += ev * f3.y; }
        U4ACC(r0, 0) U4ACC(r1, 8)
#undef U4ACC
    }
    float inv = 1.f / (den + EPSV);
    const float4* bp = (const float4*)(b1 + hh * 16);
    const float4* wp = (const float4*)(W2 + hh * 16);
    float gv = 0.f;
#pragma unroll
    for (int q = 0; q < 4; ++q) {
        float4 bb = bp[q], w2 = wp[q];
        float v0 = acc[4*q+0] * inv + bb.x; v0 = v0 > 0.f ? v0 : __expf(v0) - 1.f;
        float v1 = acc[4*q+1] * inv + bb.y; v1 = v1 > 0.f ? v1 : __expf(v1) - 1.f;
        float v2 = acc[4*q+2] * inv + bb.z; v2 = v2 > 0.f ? v2 : __expf(v2) - 1.f;
        float v3 = acc[4*q+3] * inv + bb.w; v3 = v3 > 0.f ? v3 : __expf(v3) - 1.f;
        gv += v0 * w2.x + v1 * w2.y + v2 * w2.z + v3 * w2.w;
    }
    gv += __shfl_xor(gv, 1);
    gv += __shfl_xor(gv, 2);
    if (hh == 0) g[n] = gv;
}

// ---- Layer 2 aggregation: 16 lanes per node, 16 edges in parallel ----
__global__ __launch_bounds__(256) void k_e2agg(
    const int* __restrict__ rowptr, const int* __restrict__ csr,
    const float* __restrict__ g, const float* __restrict__ att_s2,
    const float* __restrict__ att_d2, const float* __restrict__ b2,
    float* __restrict__ out)
{
    int t = threadIdx.x;
    int grp = t >> 4, cc = t & 15;
    int n = blockIdx.x * 16 + grp;     // NN/16 = 6250 exact
    float cs = att_s2[0];
    float gdcd = g[n] * att_d2[0];
    int beg = rowptr[n], end = rowptr[n + 1];
    float acc = 0.f, den = 0.f;
    for (int j = beg + cc; j < end; j += 16) {
        float gz = g[csr[j]];
        float a = gz * cs + gdcd;
        a = a > 0.f ? a : NEG * a;
        float ev = __expf(a);
        den += ev;
        acc += ev * gz;
    }
#pragma unroll
    for (int m = 1; m <= 8; m <<= 1) {
        acc += __shfl_xor(acc, m);
        den += __shfl_xor(den, m);
    }
    if (cc == 0) out[n] = acc / (den + EPSV) + b2[0];
}

extern "C" void kernel_launch(void* const* d_in, const int* in_sizes, int n_in,
                              void* d_out, int out_size, void* d_ws, size_t ws_size,
                              hipStream_t stream)
{
    const float* x   = (const float*)d_in[0];
    const int*   ei  = (const int*)d_in[1];
    const float* W1  = (const float*)d_in[2];
    const float* as1 = (const float*)d_in[3];
    const float* ad1 = (const float*)d_in[4];
    const float* b1  = (const float*)d_in[5];
    const float* W2  = (const float*)d_in[6];
    const float* as2 = (const float*)d_in[7];
    const float* ad2 = (const float*)d_in[8];
    const float* b2  = (const float*)d_in[9];
    float* out = (float*)d_out;

    // workspace layout (4-byte units, 128-slot aligned blocks)
    int*   iw      = (int*)d_ws;
    float* fw      = (float*)d_ws;
    int*   bcnt    = iw;                  //      391
    int*   bbase   = iw + 512;            //      391
    int*   bcursor = iw + 1024;           //      391
    int*   rowptr  = iw + 1536;           //  100,001
    int*   bin     = iw + 101632;         // 1,700,000
    int*   csr     = iw + 1801728;        // 1,700,000
    float* adst1   = fw + 3501824;        //   400,000
    float* asrc1   = fw + 3901952;        //   400,000
    float* g       = fw + 4302080;        //   100,000
    __half* h1h    = (__half*)(fw + 4402176); // 6.4M halves
    // total ≈ 7.6M slots ≈ 30.4 MB

    hipMemsetAsync(bcnt, 0, NB * sizeof(int), stream);

    k_bcount<<<NBLK, BS, 0, stream>>>(ei, bcnt);
    k_bscan <<<1, 512, 0, stream>>>(bcnt, bbase, bcursor, rowptr);
    k_bscat <<<NBLK, BS, 0, stream>>>(ei, bcursor, bin);
    k_bcsr  <<<NB, 256, 0, stream>>>(bin, bbase, bcnt, rowptr, csr);
    k_gemm1 <<<GEMM_BLK, 256, 0, stream>>>(x, W1, as1, ad1, h1h, asrc1, adst1);
    k_e1agg <<<(NN * 4 + 255) / 256, 256, 0, stream>>>(rowptr, csr, asrc1, adst1, h1h, b1, W2, g);
    k_e2agg <<<NN / 16, 256, 0, stream>>>(rowptr, csr, g, as2, ad2, b2, out);
}

// Round 12
// 249.575 us; speedup vs baseline: 1.1017x; 1.0856x over previous
//
#include <hip/hip_runtime.h>
#include <hip/hip_fp16.h>

#define NN   100000
#define E0   1600000
#define ET   1700000
#define NEG  0.2f
#define EPSV 1e-16f
#define NB   391            // dst buckets of 256 node ids
#define BS   1024
#define NBLK ((ET + BS - 1) / BS)   // 1661

typedef _Float16 half8 __attribute__((ext_vector_type(8)));
typedef float f32x16 __attribute__((ext_vector_type(16)));

// ---- bucket counts: LDS-aggregated histogram over 391 dst buckets ----
__global__ __launch_bounds__(BS) void k_bcount(const int* __restrict__ ei, int* __restrict__ bcnt)
{
    __shared__ int cnt[NB];
    int t = threadIdx.x;
    if (t < NB) cnt[t] = 0;
    __syncthreads();
    int idx = blockIdx.x * BS + t;
    if (idx < ET) {
        int d = (idx < E0) ? ei[E0 + idx] : (idx - E0);
        atomicAdd(&cnt[d >> 8], 1);
    }
    __syncthreads();
    if (t < NB && cnt[t]) atomicAdd(&bcnt[t], cnt[t]);
}

// ---- exclusive scan of 391 bucket counts -> bbase, bcursor; rowptr sentinel ----
__global__ __launch_bounds__(512) void k_bscan(const int* __restrict__ bcnt,
                                               int* __restrict__ bbase, int* __restrict__ bcursor,
                                               int* __restrict__ rowptr)
{
    int t = threadIdx.x;
    int v = (t < NB) ? bcnt[t] : 0;
    int lane = t & 63, wid = t >> 6;
    int sc = v;
#pragma unroll
    for (int off = 1; off < 64; off <<= 1) {
        int u = __shfl_up(sc, off, 64);
        if (lane >= off) sc += u;
    }
    __shared__ int wsum[8];
    if (lane == 63) wsum[wid] = sc;
    __syncthreads();
    int woff = 0;
    for (int k = 0; k < wid; ++k) woff += wsum[k];
    if (t < NB) { int e = sc + woff - v; bbase[t] = e; bcursor[t] = e; }
    if (t == 0) rowptr[NN] = ET;
}

// ---- bin edges by dst bucket; packed record = s | (d&255)<<17 (s < 2^17) ----
__global__ __launch_bounds__(BS) void k_bscat(const int* __restrict__ ei,
                                              int* __restrict__ bcursor, int* __restrict__ bin)
{
    __shared__ int cnt[NB];
    __shared__ int base[NB];
    int t = threadIdx.x;
    if (t < NB) cnt[t] = 0;
    __syncthreads();
    int idx = blockIdx.x * BS + t;
    int b = 0, r = 0, pk = 0;
    if (idx < ET) {
        int s, d;
        if (idx < E0) { s = ei[idx]; d = ei[E0 + idx]; } else { s = d = idx - E0; }
        b = d >> 8;
        pk = s | ((d & 255) << 17);
        r = atomicAdd(&cnt[b], 1);
    }
    __syncthreads();
    if (t < NB && cnt[t]) base[t] = atomicAdd(&bcursor[t], cnt[t]);
    __syncthreads();
    if (idx < ET) bin[base[b] + r] = pk;
}

// ---- per-bucket CSR: local deg hist, local scan -> rowptr, local scatter -> csr ----
__global__ __launch_bounds__(256) void k_bcsr(const int* __restrict__ bin,
                                              const int* __restrict__ bbase, const int* __restrict__ bcnt,
                                              int* __restrict__ rowptr, int* __restrict__ csr)
{
    int b = blockIdx.x;
    int beg = bbase[b], cntB = bcnt[b];
    int t = threadIdx.x;
    __shared__ int deg[256];
    __shared__ int cur[256];
    deg[t] = 0;
    __syncthreads();
    for (int i = t; i < cntB; i += 256) atomicAdd(&deg[bin[beg + i] >> 17], 1);
    __syncthreads();
    int v = deg[t];
    int lane = t & 63, wid = t >> 6;
    int sc = v;
#pragma unroll
    for (int off = 1; off < 64; off <<= 1) {
        int u = __shfl_up(sc, off, 64);
        if (lane >= off) sc += u;
    }
    __shared__ int wsum[4];
    if (lane == 63) wsum[wid] = sc;
    __syncthreads();
    int woff = 0;
    for (int k = 0; k < wid; ++k) woff += wsum[k];
    int excl = sc - v + woff;
    cur[t] = excl;
    int node = (b << 8) + t;
    if (node < NN) rowptr[node] = beg + excl;
    __syncthreads();
    for (int i = t; i < cntB; i += 256) {
        int e = bin[beg + i];
        int r = atomicAdd(&cur[e >> 17], 1);
        csr[beg + r] = e & 0x1FFFF;
    }
}

// ---- prep: U[k][0..3] = W1@att_src per head, U[k][4..7] = W1@att_dst.
// Logits then come out of the GEMM MFMAs directly (a_src[n][h] = x[n]. U_h). ----
__global__ __launch_bounds__(64) void k_prep(const float* __restrict__ W1,
                                             const float* __restrict__ as1, const float* __restrict__ ad1,
                                             float* __restrict__ U)
{
    int k = threadIdx.x;
#pragma unroll
    for (int h = 0; h < 4; ++h) {
        float su = 0.f, du = 0.f;
#pragma unroll
        for (int c = 0; c < 16; ++c) {
            float w = W1[k * 64 + h * 16 + c];
            su += w * as1[h * 16 + c];
            du += w * ad1[h * 16 + c];
        }
        U[k * 8 + h] = su;
        U[k * 8 + 4 + h] = du;
    }
}

// ---- Layer 1 GEMM via MFMA (VALU versions R6-R11 all ~55us: operand
// delivery bound, 64 ds_read_b32/node). One wave = 32-node tile.
// B frags (W1 + U, fp16) built once from LDS, held in VGPRs; K-loop is
// 12 x v_mfma_f32_32x32x16_f16 with zero DS traffic. ----
__global__ __launch_bounds__(256) void k_gemm1(
    const float* __restrict__ x, const float* __restrict__ W1,
    const float* __restrict__ U,
    __half* __restrict__ h1h, float* __restrict__ asrc1, float* __restrict__ adst1)
{
    __shared__ float Wl[4096];
    __shared__ float Ul[512];
    int tid = threadIdx.x;
    for (int i = tid; i < 4096; i += 256) Wl[i] = W1[i];
    if (tid < 256) { Ul[tid] = U[tid]; Ul[tid + 256] = U[tid + 256]; }
    __syncthreads();
    int lane = tid & 63, wv = tid >> 6;
    int col = lane & 31, q = lane >> 5;

    // B fragments: B[k][n], n = col, k = kc*16 + q*8 + j
    half8 bf0[4], bf1[4], bf2[4];
#pragma unroll
    for (int kc = 0; kc < 4; ++kc) {
#pragma unroll
        for (int j = 0; j < 8; ++j) {
            int k = kc * 16 + q * 8 + j;
            bf0[kc][j] = (_Float16)Wl[k * 64 + col];
            bf1[kc][j] = (_Float16)Wl[k * 64 + 32 + col];
            bf2[kc][j] = (col < 8) ? (_Float16)Ul[k * 8 + col] : (_Float16)0.f;
        }
    }

    int tile = blockIdx.x * 4 + wv;
    int n0 = tile * 32;
    if (n0 >= NN) return;

    // A fragments: A[m][k], m = col, k = kc*16 + q*8 + j (x row, fp32->fp16)
    half8 af[4];
    const float* xrow = x + (size_t)(n0 + col) * 64;
#pragma unroll
    for (int kc = 0; kc < 4; ++kc) {
        float4 xa = *(const float4*)(xrow + kc * 16 + q * 8);
        float4 xb = *(const float4*)(xrow + kc * 16 + q * 8 + 4);
        af[kc][0] = (_Float16)xa.x; af[kc][1] = (_Float16)xa.y;
        af[kc][2] = (_Float16)xa.z; af[kc][3] = (_Float16)xa.w;
        af[kc][4] = (_Float16)xb.x; af[kc][5] = (_Float16)xb.y;
        af[kc][6] = (_Float16)xb.z; af[kc][7] = (_Float16)xb.w;
    }

    f32x16 c0 = {}, c1 = {}, c2 = {};
#pragma unroll
    for (int kc = 0; kc < 4; ++kc) {
        c0 = __builtin_amdgcn_mfma_f32_32x32x16_f16(af[kc], bf0[kc], c0, 0, 0, 0);
        c1 = __builtin_amdgcn_mfma_f32_32x32x16_f16(af[kc], bf1[kc], c1, 0, 0, 0);
        c2 = __builtin_amdgcn_mfma_f32_32x32x16_f16(af[kc], bf2[kc], c2, 0, 0, 0);
    }

    // C/D layout (HW-verified): col = lane&31, row = (reg&3) + 8*(reg>>2) + 4*q
#pragma unroll
    for (int reg = 0; reg < 16; ++reg) {
        int row = (reg & 3) + 8 * (reg >> 2) + 4 * q;
        h1h[(size_t)(n0 + row) * 64 + col]      = __float2half(c0[reg]);
        h1h[(size_t)(n0 + row) * 64 + 32 + col] = __float2half(c1[reg]);
    }
    if (col < 8) {
        float* dst = (col < 4) ? asrc1 : adst1;
        int h = col & 3;
#pragma unroll
        for (int reg = 0; reg < 16; ++reg) {
            int row = (reg & 3) + 8 * (reg >> 2) + 4 * q;
            dst[(n0 + row) * 4 + h] = c2[reg];
        }
    }
}

// ---- Layer 1 aggregation: 4 LANES PER NODE (lane = head). Each lane owns
// its head's 16 channels (16 fp32 accs), loads 32B of each gathered h1 row,
// own exp/denominator. Epilogue in-register; 2-step shfl_xor combine. ----
__global__ __launch_bounds__(256) void k_e1agg(
    const int* __restrict__ rowptr, const int* __restrict__ csr,
    const float* __restrict__ asrc1, const float* __restrict__ adst1,
    const __half* __restrict__ h1h, const float* __restrict__ b1,
    const float* __restrict__ W2, float* __restrict__ g)
{
    int t = threadIdx.x;
    int hh = t & 3;                 // head
    int n = blockIdx.x * 64 + (t >> 2);
    if (n >= NN) return;
    float ad = adst1[n * 4 + hh];
    int beg = rowptr[n], end = rowptr[n + 1];
    float acc[16];
#pragma unroll
    for (int c = 0; c < 16; ++c) acc[c] = 0.f;
    float den = 0.f;
    for (int j = beg; j < end; ++j) {
        int s = csr[j];
        float as = asrc1[s * 4 + hh];
        float a = as + ad; a = a > 0.f ? a : NEG * a;
        float ev = __expf(a);
        den += ev;
        const uint4* hp = (const uint4*)(h1h + (size_t)s * 64 + hh * 16);
        uint4 r0 = hp[0], r1 = hp[1];
#define U4ACC(r, base) { \
        float2 f0 = __half22float2(*(const __half2*)&r.x); \
        float2 f1 = __half22float2(*(const __half2*)&r.y); \
        float2 f2 = __half22float2(*(const __half2*)&r.z); \
        float2 f3 = __half22float2(*(const __half2*)&r.w); \
        acc[base+0] += ev * f0.x; acc[base+1] += ev * f0.y; \
        acc[base+2] += ev * f1.x; acc[base+3] += ev * f1.y; \
        acc[base+4] += ev * f2.x; acc[base+5] += ev * f2.y; \
        acc[base+6] += ev * f3.x; acc[base+7] += ev * f3.y; }
        U4ACC(r0, 0) U4ACC(r1, 8)
#undef U4ACC
    }
    float inv = 1.f / (den + EPSV);
    const float4* bp = (const float4*)(b1 + hh * 16);
    const float4* wp = (const float4*)(W2 + hh * 16);
    float gv = 0.f;
#pragma unroll
    for (int q = 0; q < 4; ++q) {
        float4 bb = bp[q], w2 = wp[q];
        float v0 = acc[4*q+0] * inv + bb.x; v0 = v0 > 0.f ? v0 : __expf(v0) - 1.f;
        float v1 = acc[4*q+1] * inv + bb.y; v1 = v1 > 0.f ? v1 : __expf(v1) - 1.f;
        float v2 = acc[4*q+2] * inv + bb.z; v2 = v2 > 0.f ? v2 : __expf(v2) - 1.f;
        float v3 = acc[4*q+3] * inv + bb.w; v3 = v3 > 0.f ? v3 : __expf(v3) - 1.f;
        gv += v0 * w2.x + v1 * w2.y + v2 * w2.z + v3 * w2.w;
    }
    gv += __shfl_xor(gv, 1);
    gv += __shfl_xor(gv, 2);
    if (hh == 0) g[n] = gv;
}

// ---- Layer 2 aggregation: 16 lanes per node, 16 edges in parallel ----
__global__ __launch_bounds__(256) void k_e2agg(
    const int* __restrict__ rowptr, const int* __restrict__ csr,
    const float* __restrict__ g, const float* __restrict__ att_s2,
    const float* __restrict__ att_d2, const float* __restrict__ b2,
    float* __restrict__ out)
{
    int t = threadIdx.x;
    int grp = t >> 4, cc = t & 15;
    int n = blockIdx.x * 16 + grp;     // NN/16 = 6250 exact
    float cs = att_s2[0];
    float gdcd = g[n] * att_d2[0];
    int beg = rowptr[n], end = rowptr[n + 1];
    float acc = 0.f, den = 0.f;
    for (int j = beg + cc; j < end; j += 16) {
        float gz = g[csr[j]];
        float a = gz * cs + gdcd;
        a = a > 0.f ? a : NEG * a;
        float ev = __expf(a);
        den += ev;
        acc += ev * gz;
    }
#pragma unroll
    for (int m = 1; m <= 8; m <<= 1) {
        acc += __shfl_xor(acc, m);
        den += __shfl_xor(den, m);
    }
    if (cc == 0) out[n] = acc / (den + EPSV) + b2[0];
}

extern "C" void kernel_launch(void* const* d_in, const int* in_sizes, int n_in,
                              void* d_out, int out_size, void* d_ws, size_t ws_size,
                              hipStream_t stream)
{
    const float* x   = (const float*)d_in[0];
    const int*   ei  = (const int*)d_in[1];
    const float* W1  = (const float*)d_in[2];
    const float* as1 = (const float*)d_in[3];
    const float* ad1 = (const float*)d_in[4];
    const float* b1  = (const float*)d_in[5];
    const float* W2  = (const float*)d_in[6];
    const float* as2 = (const float*)d_in[7];
    const float* ad2 = (const float*)d_in[8];
    const float* b2  = (const float*)d_in[9];
    float* out = (float*)d_out;

    // workspace layout (4-byte units, 128-slot aligned blocks)
    int*   iw      = (int*)d_ws;
    float* fw      = (float*)d_ws;
    int*   bcnt    = iw;                  //      391
    int*   bbase   = iw + 512;            //      391
    int*   bcursor = iw + 1024;           //      391
    int*   rowptr  = iw + 1536;           //  100,001
    int*   bin     = iw + 101632;         // 1,700,000
    int*   csr     = iw + 1801728;        // 1,700,000
    float* adst1   = fw + 3501824;        //   400,000
    float* asrc1   = fw + 3901952;        //   400,000
    float* g       = fw + 4302080;        //   100,000
    float* U       = fw + 4402176;        //       512
    __half* h1h    = (__half*)(fw + 4403200); // 6.4M halves
    // total ≈ 7.6M slots ≈ 30.4 MB

    hipMemsetAsync(bcnt, 0, NB * sizeof(int), stream);

    k_bcount<<<NBLK, BS, 0, stream>>>(ei, bcnt);
    k_bscan <<<1, 512, 0, stream>>>(bcnt, bbase, bcursor, rowptr);
    k_bscat <<<NBLK, BS, 0, stream>>>(ei, bcursor, bin);
    k_bcsr  <<<NB, 256, 0, stream>>>(bin, bbase, bcnt, rowptr, csr);
    k_prep  <<<1, 64, 0, stream>>>(W1, as1, ad1, U);
    k_gemm1 <<<(NN / 32 + 3) / 4, 256, 0, stream>>>(x, W1, U, h1h, asrc1, adst1);
    k_e1agg <<<(NN * 4 + 255) / 256, 256, 0, stream>>>(rowptr, csr, asrc1, adst1, h1h, b1, W2, g);
    k_e2agg <<<NN / 16, 256, 0, stream>>>(rowptr, csr, g, as2, ad2, b2, out);
}

// Round 13
// 230.882 us; speedup vs baseline: 1.1909x; 1.0810x over previous
//
#include <hip/hip_runtime.h>
#include <hip/hip_fp16.h>

#define NN   100000
#define E0   1600000
#define ET   1700000
#define NEG  0.2f
#define EPSV 1e-16f
#define NB   391            // dst buckets of 256 node ids
#define BS   1024
#define NBLK4 ((ET + 4 * BS - 1) / (4 * BS))   // 416, 4 edges/thread

typedef _Float16 half8 __attribute__((ext_vector_type(8)));
typedef float f32x16 __attribute__((ext_vector_type(16)));

// ---- bucket counts: LDS-aggregated histogram, 4 edges/thread ----
__global__ __launch_bounds__(BS) void k_bcount(const int* __restrict__ ei, int* __restrict__ bcnt)
{
    __shared__ int cnt[NB];
    int t = threadIdx.x;
    if (t < NB) cnt[t] = 0;
    __syncthreads();
    int base = blockIdx.x * (BS * 4);
#pragma unroll
    for (int k = 0; k < 4; ++k) {
        int idx = base + k * BS + t;
        if (idx < ET) {
            int d = (idx < E0) ? ei[E0 + idx] : (idx - E0);
            atomicAdd(&cnt[d >> 8], 1);
        }
    }
    __syncthreads();
    if (t < NB && cnt[t]) atomicAdd(&bcnt[t], cnt[t]);
}

// ---- exclusive scan of 391 bucket counts -> bbase, bcursor; rowptr sentinel ----
__global__ __launch_bounds__(512) void k_bscan(const int* __restrict__ bcnt,
                                               int* __restrict__ bbase, int* __restrict__ bcursor,
                                               int* __restrict__ rowptr)
{
    int t = threadIdx.x;
    int v = (t < NB) ? bcnt[t] : 0;
    int lane = t & 63, wid = t >> 6;
    int sc = v;
#pragma unroll
    for (int off = 1; off < 64; off <<= 1) {
        int u = __shfl_up(sc, off, 64);
        if (lane >= off) sc += u;
    }
    __shared__ int wsum[8];
    if (lane == 63) wsum[wid] = sc;
    __syncthreads();
    int woff = 0;
    for (int k = 0; k < wid; ++k) woff += wsum[k];
    if (t < NB) { int e = sc + woff - v; bbase[t] = e; bcursor[t] = e; }
    if (t == 0) rowptr[NN] = ET;
}

// ---- bin edges by dst bucket, 4 edges/thread; record = s | (d&255)<<17 ----
__global__ __launch_bounds__(BS) void k_bscat(const int* __restrict__ ei,
                                              int* __restrict__ bcursor, int* __restrict__ bin)
{
    __shared__ int cnt[NB];
    __shared__ int base[NB];
    int t = threadIdx.x;
    if (t < NB) cnt[t] = 0;
    __syncthreads();
    int blk = blockIdx.x * (BS * 4);
    int b[4], r[4], pk[4];
#pragma unroll
    for (int k = 0; k < 4; ++k) {
        int idx = blk + k * BS + t;
        r[k] = -1;
        if (idx < ET) {
            int s, d;
            if (idx < E0) { s = ei[idx]; d = ei[E0 + idx]; } else { s = d = idx - E0; }
            b[k] = d >> 8;
            pk[k] = s | ((d & 255) << 17);
            r[k] = atomicAdd(&cnt[b[k]], 1);
        }
    }
    __syncthreads();
    if (t < NB && cnt[t]) base[t] = atomicAdd(&bcursor[t], cnt[t]);
    __syncthreads();
#pragma unroll
    for (int k = 0; k < 4; ++k)
        if (r[k] >= 0) bin[base[b[k]] + r[k]] = pk[k];
}

// ---- per-bucket CSR: local deg hist, local scan -> rowptr, local scatter -> csr ----
__global__ __launch_bounds__(256) void k_bcsr(const int* __restrict__ bin,
                                              const int* __restrict__ bbase, const int* __restrict__ bcnt,
                                              int* __restrict__ rowptr, int* __restrict__ csr)
{
    int b = blockIdx.x;
    int beg = bbase[b], cntB = bcnt[b];
    int t = threadIdx.x;
    __shared__ int deg[256];
    __shared__ int cur[256];
    deg[t] = 0;
    __syncthreads();
    for (int i = t; i < cntB; i += 256) atomicAdd(&deg[bin[beg + i] >> 17], 1);
    __syncthreads();
    int v = deg[t];
    int lane = t & 63, wid = t >> 6;
    int sc = v;
#pragma unroll
    for (int off = 1; off < 64; off <<= 1) {
        int u = __shfl_up(sc, off, 64);
        if (lane >= off) sc += u;
    }
    __shared__ int wsum[4];
    if (lane == 63) wsum[wid] = sc;
    __syncthreads();
    int woff = 0;
    for (int k = 0; k < wid; ++k) woff += wsum[k];
    int excl = sc - v + woff;
    cur[t] = excl;
    int node = (b << 8) + t;
    if (node < NN) rowptr[node] = beg + excl;
    __syncthreads();
    for (int i = t; i < cntB; i += 256) {
        int e = bin[beg + i];
        int r = atomicAdd(&cur[e >> 17], 1);
        csr[beg + r] = e & 0x1FFFF;
    }
}

// ---- Layer 1 GEMM via MFMA. U (= W1@att_src | W1@att_dst) computed in-block
// from the staged W1 (k_prep folded in). One wave = 32-node tile; B frags in
// VGPRs; K-loop = 12 v_mfma_f32_32x32x16_f16, zero DS traffic. ----
__global__ __launch_bounds__(256) void k_gemm1(
    const float* __restrict__ x, const float* __restrict__ W1,
    const float* __restrict__ as1, const float* __restrict__ ad1,
    __half* __restrict__ h1h, float* __restrict__ asrc1, float* __restrict__ adst1)
{
    __shared__ float Wl[4096];
    __shared__ float Ul[512];
    int tid = threadIdx.x;
    for (int i = tid; i < 4096; i += 256) Wl[i] = W1[i];
    __syncthreads();
    if (tid < 64) {
        int k = tid;
#pragma unroll
        for (int h = 0; h < 4; ++h) {
            float su = 0.f, du = 0.f;
#pragma unroll
            for (int c = 0; c < 16; ++c) {
                float w = Wl[k * 64 + h * 16 + c];
                su += w * as1[h * 16 + c];
                du += w * ad1[h * 16 + c];
            }
            Ul[k * 8 + h] = su;
            Ul[k * 8 + 4 + h] = du;
        }
    }
    __syncthreads();
    int lane = tid & 63, wv = tid >> 6;
    int col = lane & 31, q = lane >> 5;

    // B fragments: B[k][n], n = col, k = kc*16 + q*8 + j
    half8 bf0[4], bf1[4], bf2[4];
#pragma unroll
    for (int kc = 0; kc < 4; ++kc) {
#pragma unroll
        for (int j = 0; j < 8; ++j) {
            int k = kc * 16 + q * 8 + j;
            bf0[kc][j] = (_Float16)Wl[k * 64 + col];
            bf1[kc][j] = (_Float16)Wl[k * 64 + 32 + col];
            bf2[kc][j] = (col < 8) ? (_Float16)Ul[k * 8 + col] : (_Float16)0.f;
        }
    }

    int tile = blockIdx.x * 4 + wv;
    int n0 = tile * 32;
    if (n0 >= NN) return;

    // A fragments: A[m][k], m = col, k = kc*16 + q*8 + j (x row, fp32->fp16)
    half8 af[4];
    const float* xrow = x + (size_t)(n0 + col) * 64;
#pragma unroll
    for (int kc = 0; kc < 4; ++kc) {
        float4 xa = *(const float4*)(xrow + kc * 16 + q * 8);
        float4 xb = *(const float4*)(xrow + kc * 16 + q * 8 + 4);
        af[kc][0] = (_Float16)xa.x; af[kc][1] = (_Float16)xa.y;
        af[kc][2] = (_Float16)xa.z; af[kc][3] = (_Float16)xa.w;
        af[kc][4] = (_Float16)xb.x; af[kc][5] = (_Float16)xb.y;
        af[kc][6] = (_Float16)xb.z; af[kc][7] = (_Float16)xb.w;
    }

    f32x16 c0 = {}, c1 = {}, c2 = {};
#pragma unroll
    for (int kc = 0; kc < 4; ++kc) {
        c0 = __builtin_amdgcn_mfma_f32_32x32x16_f16(af[kc], bf0[kc], c0, 0, 0, 0);
        c1 = __builtin_amdgcn_mfma_f32_32x32x16_f16(af[kc], bf1[kc], c1, 0, 0, 0);
        c2 = __builtin_amdgcn_mfma_f32_32x32x16_f16(af[kc], bf2[kc], c2, 0, 0, 0);
    }

    // C/D layout (HW-verified): col = lane&31, row = (reg&3) + 8*(reg>>2) + 4*q
#pragma unroll
    for (int reg = 0; reg < 16; ++reg) {
        int row = (reg & 3) + 8 * (reg >> 2) + 4 * q;
        h1h[(size_t)(n0 + row) * 64 + col]      = __float2half(c0[reg]);
        h1h[(size_t)(n0 + row) * 64 + 32 + col] = __float2half(c1[reg]);
    }
    if (col < 8) {
        float* dst = (col < 4) ? asrc1 : adst1;
        int h = col & 3;
#pragma unroll
        for (int reg = 0; reg < 16; ++reg) {
            int row = (reg & 3) + 8 * (reg >> 2) + 4 * q;
            dst[(n0 + row) * 4 + h] = c2[reg];
        }
    }
}

// ---- Layer 1 aggregation: 4 lanes/node (lane = head), UNROLL x2 for MLP.
// Each lane: 16 fp32 accs, 2x(2 x 16B) h1 loads + 2 asrc loads in flight. ----
__global__ __launch_bounds__(256) void k_e1agg(
    const int* __restrict__ rowptr, const int* __restrict__ csr,
    const float* __restrict__ asrc1, const float* __restrict__ adst1,
    const __half* __restrict__ h1h, const float* __restrict__ b1,
    const float* __restrict__ W2, float* __restrict__ g)
{
    int t = threadIdx.x;
    int hh = t & 3;                 // head
    int n = blockIdx.x * 64 + (t >> 2);
    if (n >= NN) return;
    float ad = adst1[n * 4 + hh];
    int beg = rowptr[n], end = rowptr[n + 1];
    float acc[16];
#pragma unroll
    for (int c = 0; c < 16; ++c) acc[c] = 0.f;
    float den = 0.f;
#define U4ACC(r, base, e) { \
        float2 f0 = __half22float2(*(const __half2*)&r.x); \
        float2 f1 = __half22float2(*(const __half2*)&r.y); \
        float2 f2 = __half22float2(*(const __half2*)&r.z); \
        float2 f3 = __half22float2(*(const __half2*)&r.w); \
        acc[base+0] += e * f0.x; acc[base+1] += e * f0.y; \
        acc[base+2] += e * f1.x; acc[base+3] += e * f1.y; \
        acc[base+4] += e * f2.x; acc[base+5] += e * f2.y; \
        acc[base+6] += e * f3.x; acc[base+7] += e * f3.y; }
    int j = beg;
    for (; j + 2 <= end; j += 2) {
        int s0 = csr[j], s1 = csr[j + 1];
        const uint4* hp0 = (const uint4*)(h1h + (size_t)s0 * 64 + hh * 16);
        const uint4* hp1 = (const uint4*)(h1h + (size_t)s1 * 64 + hh * 16);
        float as0 = asrc1[s0 * 4 + hh];
        float as1v = asrc1[s1 * 4 + hh];
        uint4 p0 = hp0[0], p1 = hp0[1];
        uint4 q0 = hp1[0], q1 = hp1[1];
        float a0 = as0 + ad;  a0 = a0 > 0.f ? a0 : NEG * a0;
        float a1 = as1v + ad; a1 = a1 > 0.f ? a1 : NEG * a1;
        float e0 = __expf(a0), e1 = __expf(a1);
        den += e0 + e1;
        U4ACC(p0, 0, e0) U4ACC(p1, 8, e0)
        U4ACC(q0, 0, e1) U4ACC(q1, 8, e1)
    }
    if (j < end) {
        int s = csr[j];
        const uint4* hp = (const uint4*)(h1h + (size_t)s * 64 + hh * 16);
        float as = asrc1[s * 4 + hh];
        uint4 p0 = hp[0], p1 = hp[1];
        float a = as + ad; a = a > 0.f ? a : NEG * a;
        float ev = __expf(a);
        den += ev;
        U4ACC(p0, 0, ev) U4ACC(p1, 8, ev)
    }
#undef U4ACC
    float inv = 1.f / (den + EPSV);
    const float4* bp = (const float4*)(b1 + hh * 16);
    const float4* wp = (const float4*)(W2 + hh * 16);
    float gv = 0.f;
#pragma unroll
    for (int q = 0; q < 4; ++q) {
        float4 bb = bp[q], w2 = wp[q];
        float v0 = acc[4*q+0] * inv + bb.x; v0 = v0 > 0.f ? v0 : __expf(v0) - 1.f;
        float v1 = acc[4*q+1] * inv + bb.y; v1 = v1 > 0.f ? v1 : __expf(v1) - 1.f;
        float v2 = acc[4*q+2] * inv + bb.z; v2 = v2 > 0.f ? v2 : __expf(v2) - 1.f;
        float v3 = acc[4*q+3] * inv + bb.w; v3 = v3 > 0.f ? v3 : __expf(v3) - 1.f;
        gv += v0 * w2.x + v1 * w2.y + v2 * w2.z + v3 * w2.w;
    }
    gv += __shfl_xor(gv, 1);
    gv += __shfl_xor(gv, 2);
    if (hh == 0) g[n] = gv;
}

// ---- Layer 2 aggregation: 16 lanes per node, 16 edges in parallel ----
__global__ __launch_bounds__(256) void k_e2agg(
    const int* __restrict__ rowptr, const int* __restrict__ csr,
    const float* __restrict__ g, const float* __restrict__ att_s2,
    const float* __restrict__ att_d2, const float* __restrict__ b2,
    float* __restrict__ out)
{
    int t = threadIdx.x;
    int grp = t >> 4, cc = t & 15;
    int n = blockIdx.x * 16 + grp;     // NN/16 = 6250 exact
    float cs = att_s2[0];
    float gdcd = g[n] * att_d2[0];
    int beg = rowptr[n], end = rowptr[n + 1];
    float acc = 0.f, den = 0.f;
    for (int j = beg + cc; j < end; j += 16) {
        float gz = g[csr[j]];
        float a = gz * cs + gdcd;
        a = a > 0.f ? a : NEG * a;
        float ev = __expf(a);
        den += ev;
        acc += ev * gz;
    }
#pragma unroll
    for (int m = 1; m <= 8; m <<= 1) {
        acc += __shfl_xor(acc, m);
        den += __shfl_xor(den, m);
    }
    if (cc == 0) out[n] = acc / (den + EPSV) + b2[0];
}

extern "C" void kernel_launch(void* const* d_in, const int* in_sizes, int n_in,
                              void* d_out, int out_size, void* d_ws, size_t ws_size,
                              hipStream_t stream)
{
    const float* x   = (const float*)d_in[0];
    const int*   ei  = (const int*)d_in[1];
    const float* W1  = (const float*)d_in[2];
    const float* as1 = (const float*)d_in[3];
    const float* ad1 = (const float*)d_in[4];
    const float* b1  = (const float*)d_in[5];
    const float* W2  = (const float*)d_in[6];
    const float* as2 = (const float*)d_in[7];
    const float* ad2 = (const float*)d_in[8];
    const float* b2  = (const float*)d_in[9];
    float* out = (float*)d_out;

    // workspace layout (4-byte units, 128-slot aligned blocks)
    int*   iw      = (int*)d_ws;
    float* fw      = (float*)d_ws;
    int*   bcnt    = iw;                  //      391
    int*   bbase   = iw + 512;            //      391
    int*   bcursor = iw + 1024;           //      391
    int*   rowptr  = iw + 1536;           //  100,001
    int*   bin     = iw + 101632;         // 1,700,000
    int*   csr     = iw + 1801728;        // 1,700,000
    float* adst1   = fw + 3501824;        //   400,000
    float* asrc1   = fw + 3901952;        //   400,000
    float* g       = fw + 4302080;        //   100,000
    __half* h1h    = (__half*)(fw + 4402176); // 6.4M halves
    // total ≈ 7.6M slots ≈ 30.4 MB

    hipMemsetAsync(bcnt, 0, NB * sizeof(int), stream);

    k_bcount<<<NBLK4, BS, 0, stream>>>(ei, bcnt);
    k_bscan <<<1, 512, 0, stream>>>(bcnt, bbase, bcursor, rowptr);
    k_bscat <<<NBLK4, BS, 0, stream>>>(ei, bcursor, bin);
    k_bcsr  <<<NB, 256, 0, stream>>>(bin, bbase, bcnt, rowptr, csr);
    k_gemm1 <<<(NN / 32 + 3) / 4, 256, 0, stream>>>(x, W1, as1, ad1, h1h, asrc1, adst1);
    k_e1agg <<<(NN * 4 + 255) / 256, 256, 0, stream>>>(rowptr, csr, asrc1, adst1, h1h, b1, W2, g);
    k_e2agg <<<NN / 16, 256, 0, stream>>>(rowptr, csr, g, as2, ad2, b2, out);
}

// Round 14
// 213.392 us; speedup vs baseline: 1.2885x; 1.0820x over previous
//
#include <hip/hip_runtime.h>
#include <hip/hip_fp16.h>

#define NN   100000
#define E0   1600000
#define ET   1700000
#define NEG  0.2f
#define EPSV 1e-16f
#define NB   391            // dst buckets of 256 node ids
#define BS   1024
#define NBLK4 ((ET + 4 * BS - 1) / (4 * BS))   // 416, 4 edges/thread

typedef _Float16 half8 __attribute__((ext_vector_type(8)));
typedef float f32x16 __attribute__((ext_vector_type(16)));

// ---- bucket counts: LDS-aggregated histogram, 4 edges/thread ----
__global__ __launch_bounds__(BS) void k_bcount(const int* __restrict__ ei, int* __restrict__ bcnt)
{
    __shared__ int cnt[NB];
    int t = threadIdx.x;
    if (t < NB) cnt[t] = 0;
    __syncthreads();
    int base = blockIdx.x * (BS * 4);
#pragma unroll
    for (int k = 0; k < 4; ++k) {
        int idx = base + k * BS + t;
        if (idx < ET) {
            int d = (idx < E0) ? ei[E0 + idx] : (idx - E0);
            atomicAdd(&cnt[d >> 8], 1);
        }
    }
    __syncthreads();
    if (t < NB && cnt[t]) atomicAdd(&bcnt[t], cnt[t]);
}

// ---- exclusive scan of 391 bucket counts -> bbase, bcursor; rowptr sentinel ----
__global__ __launch_bounds__(512) void k_bscan(const int* __restrict__ bcnt,
                                               int* __restrict__ bbase, int* __restrict__ bcursor,
                                               int* __restrict__ rowptr)
{
    int t = threadIdx.x;
    int v = (t < NB) ? bcnt[t] : 0;
    int lane = t & 63, wid = t >> 6;
    int sc = v;
#pragma unroll
    for (int off = 1; off < 64; off <<= 1) {
        int u = __shfl_up(sc, off, 64);
        if (lane >= off) sc += u;
    }
    __shared__ int wsum[8];
    if (lane == 63) wsum[wid] = sc;
    __syncthreads();
    int woff = 0;
    for (int k = 0; k < wid; ++k) woff += wsum[k];
    if (t < NB) { int e = sc + woff - v; bbase[t] = e; bcursor[t] = e; }
    if (t == 0) rowptr[NN] = ET;
}

// ---- bin edges by dst bucket, 4 edges/thread; record = s | (d&255)<<17 ----
__global__ __launch_bounds__(BS) void k_bscat(const int* __restrict__ ei,
                                              int* __restrict__ bcursor, int* __restrict__ bin)
{
    __shared__ int cnt[NB];
    __shared__ int base[NB];
    int t = threadIdx.x;
    if (t < NB) cnt[t] = 0;
    __syncthreads();
    int blk = blockIdx.x * (BS * 4);
    int b[4], r[4], pk[4];
#pragma unroll
    for (int k = 0; k < 4; ++k) {
        int idx = blk + k * BS + t;
        r[k] = -1;
        if (idx < ET) {
            int s, d;
            if (idx < E0) { s = ei[idx]; d = ei[E0 + idx]; } else { s = d = idx - E0; }
            b[k] = d >> 8;
            pk[k] = s | ((d & 255) << 17);
            r[k] = atomicAdd(&cnt[b[k]], 1);
        }
    }
    __syncthreads();
    if (t < NB && cnt[t]) base[t] = atomicAdd(&bcursor[t], cnt[t]);
    __syncthreads();
#pragma unroll
    for (int k = 0; k < 4; ++k)
        if (r[k] >= 0) bin[base[b[k]] + r[k]] = pk[k];
}

// ---- per-bucket CSR: local deg hist, local scan -> rowptr, local scatter -> csr ----
__global__ __launch_bounds__(256) void k_bcsr(const int* __restrict__ bin,
                                              const int* __restrict__ bbase, const int* __restrict__ bcnt,
                                              int* __restrict__ rowptr, int* __restrict__ csr)
{
    int b = blockIdx.x;
    int beg = bbase[b], cntB = bcnt[b];
    int t = threadIdx.x;
    __shared__ int deg[256];
    __shared__ int cur[256];
    deg[t] = 0;
    __syncthreads();
    for (int i = t; i < cntB; i += 256) atomicAdd(&deg[bin[beg + i] >> 17], 1);
    __syncthreads();
    int v = deg[t];
    int lane = t & 63, wid = t >> 6;
    int sc = v;
#pragma unroll
    for (int off = 1; off < 64; off <<= 1) {
        int u = __shfl_up(sc, off, 64);
        if (lane >= off) sc += u;
    }
    __shared__ int wsum[4];
    if (lane == 63) wsum[wid] = sc;
    __syncthreads();
    int woff = 0;
    for (int k = 0; k < wid; ++k) woff += wsum[k];
    int excl = sc - v + woff;
    cur[t] = excl;
    int node = (b << 8) + t;
    if (node < NN) rowptr[node] = beg + excl;
    __syncthreads();
    for (int i = t; i < cntB; i += 256) {
        int e = bin[beg + i];
        int r = atomicAdd(&cur[e >> 17], 1);
        csr[beg + r] = e & 0x1FFFF;
    }
}

// ---- Layer 1 GEMM via MFMA. U (= W1@att_src | W1@att_dst) computed in-block
// from the staged W1. One wave = 32-node tile; B frags in VGPRs; K-loop =
// 12 v_mfma_f32_32x32x16_f16, zero DS traffic. ----
__global__ __launch_bounds__(256) void k_gemm1(
    const float* __restrict__ x, const float* __restrict__ W1,
    const float* __restrict__ as1, const float* __restrict__ ad1,
    __half* __restrict__ h1h, float* __restrict__ asrc1, float* __restrict__ adst1)
{
    __shared__ float Wl[4096];
    __shared__ float Ul[512];
    int tid = threadIdx.x;
    for (int i = tid; i < 4096; i += 256) Wl[i] = W1[i];
    __syncthreads();
    if (tid < 64) {
        int k = tid;
#pragma unroll
        for (int h = 0; h < 4; ++h) {
            float su = 0.f, du = 0.f;
#pragma unroll
            for (int c = 0; c < 16; ++c) {
                float w = Wl[k * 64 + h * 16 + c];
                su += w * as1[h * 16 + c];
                du += w * ad1[h * 16 + c];
            }
            Ul[k * 8 + h] = su;
            Ul[k * 8 + 4 + h] = du;
        }
    }
    __syncthreads();
    int lane = tid & 63, wv = tid >> 6;
    int col = lane & 31, q = lane >> 5;

    // B fragments: B[k][n], n = col, k = kc*16 + q*8 + j
    half8 bf0[4], bf1[4], bf2[4];
#pragma unroll
    for (int kc = 0; kc < 4; ++kc) {
#pragma unroll
        for (int j = 0; j < 8; ++j) {
            int k = kc * 16 + q * 8 + j;
            bf0[kc][j] = (_Float16)Wl[k * 64 + col];
            bf1[kc][j] = (_Float16)Wl[k * 64 + 32 + col];
            bf2[kc][j] = (col < 8) ? (_Float16)Ul[k * 8 + col] : (_Float16)0.f;
        }
    }

    int tile = blockIdx.x * 4 + wv;
    int n0 = tile * 32;
    if (n0 >= NN) return;

    // A fragments: A[m][k], m = col, k = kc*16 + q*8 + j (x row, fp32->fp16)
    half8 af[4];
    const float* xrow = x + (size_t)(n0 + col) * 64;
#pragma unroll
    for (int kc = 0; kc < 4; ++kc) {
        float4 xa = *(const float4*)(xrow + kc * 16 + q * 8);
        float4 xb = *(const float4*)(xrow + kc * 16 + q * 8 + 4);
        af[kc][0] = (_Float16)xa.x; af[kc][1] = (_Float16)xa.y;
        af[kc][2] = (_Float16)xa.z; af[kc][3] = (_Float16)xa.w;
        af[kc][4] = (_Float16)xb.x; af[kc][5] = (_Float16)xb.y;
        af[kc][6] = (_Float16)xb.z; af[kc][7] = (_Float16)xb.w;
    }

    f32x16 c0 = {}, c1 = {}, c2 = {};
#pragma unroll
    for (int kc = 0; kc < 4; ++kc) {
        c0 = __builtin_amdgcn_mfma_f32_32x32x16_f16(af[kc], bf0[kc], c0, 0, 0, 0);
        c1 = __builtin_amdgcn_mfma_f32_32x32x16_f16(af[kc], bf1[kc], c1, 0, 0, 0);
        c2 = __builtin_amdgcn_mfma_f32_32x32x16_f16(af[kc], bf2[kc], c2, 0, 0, 0);
    }

    // C/D layout (HW-verified): col = lane&31, row = (reg&3) + 8*(reg>>2) + 4*q
#pragma unroll
    for (int reg = 0; reg < 16; ++reg) {
        int row = (reg & 3) + 8 * (reg >> 2) + 4 * q;
        h1h[(size_t)(n0 + row) * 64 + col]      = __float2half(c0[reg]);
        h1h[(size_t)(n0 + row) * 64 + 32 + col] = __float2half(c1[reg]);
    }
    if (col < 8) {
        float* dst = (col < 4) ? asrc1 : adst1;
        int h = col & 3;
#pragma unroll
        for (int reg = 0; reg < 16; ++reg) {
            int row = (reg & 3) + 8 * (reg >> 2) + 4 * q;
            dst[(n0 + row) * 4 + h] = c2[reg];
        }
    }
}

// ---- Layer 1 aggregation: 4 lanes/node (lane = head), SINGLE-edge loop.
// (R13's x2 unroll REGRESSED: more rows in flight -> L2 reuse window
// shrinks, FETCH 128->187MB; kernel is L2-miss-traffic bound at ~2.7TB/s.) ----
__global__ __launch_bounds__(256) void k_e1agg(
    const int* __restrict__ rowptr, const int* __restrict__ csr,
    const float* __restrict__ asrc1, const float* __restrict__ adst1,
    const __half* __restrict__ h1h, const float* __restrict__ b1,
    const float* __restrict__ W2, float* __restrict__ g)
{
    int t = threadIdx.x;
    int hh = t & 3;                 // head
    int n = blockIdx.x * 64 + (t >> 2);
    if (n >= NN) return;
    float ad = adst1[n * 4 + hh];
    int beg = rowptr[n], end = rowptr[n + 1];
    float acc[16];
#pragma unroll
    for (int c = 0; c < 16; ++c) acc[c] = 0.f;
    float den = 0.f;
    for (int j = beg; j < end; ++j) {
        int s = csr[j];
        float as = asrc1[s * 4 + hh];
        float a = as + ad; a = a > 0.f ? a : NEG * a;
        float ev = __expf(a);
        den += ev;
        const uint4* hp = (const uint4*)(h1h + (size_t)s * 64 + hh * 16);
        uint4 r0 = hp[0], r1 = hp[1];
#define U4ACC(r, base) { \
        float2 f0 = __half22float2(*(const __half2*)&r.x); \
        float2 f1 = __half22float2(*(const __half2*)&r.y); \
        float2 f2 = __half22float2(*(const __half2*)&r.z); \
        float2 f3 = __half22float2(*(const __half2*)&r.w); \
        acc[base+0] += ev * f0.x; acc[base+1] += ev * f0.y; \
        acc[base+2] += ev * f1.x; acc[base+3] += ev * f1.y; \
        acc[base+4] += ev * f2.x; acc[base+5] += ev * f2.y; \
        acc[base+6] += ev * f3.x; acc[base+7] += ev * f3.y; }
        U4ACC(r0, 0) U4ACC(r1, 8)
#undef U4ACC
    }
    float inv = 1.f / (den + EPSV);
    const float4* bp = (const float4*)(b1 + hh * 16);
    const float4* wp = (const float4*)(W2 + hh * 16);
    float gv = 0.f;
#pragma unroll
    for (int q = 0; q < 4; ++q) {
        float4 bb = bp[q], w2 = wp[q];
        float v0 = acc[4*q+0] * inv + bb.x; v0 = v0 > 0.f ? v0 : __expf(v0) - 1.f;
        float v1 = acc[4*q+1] * inv + bb.y; v1 = v1 > 0.f ? v1 : __expf(v1) - 1.f;
        float v2 = acc[4*q+2] * inv + bb.z; v2 = v2 > 0.f ? v2 : __expf(v2) - 1.f;
        float v3 = acc[4*q+3] * inv + bb.w; v3 = v3 > 0.f ? v3 : __expf(v3) - 1.f;
        gv += v0 * w2.x + v1 * w2.y + v2 * w2.z + v3 * w2.w;
    }
    gv += __shfl_xor(gv, 1);
    gv += __shfl_xor(gv, 2);
    if (hh == 0) g[n] = gv;
}

// ---- Layer 2 aggregation: 16 lanes per node, 16 edges in parallel ----
__global__ __launch_bounds__(256) void k_e2agg(
    const int* __restrict__ rowptr, const int* __restrict__ csr,
    const float* __restrict__ g, const float* __restrict__ att_s2,
    const float* __restrict__ att_d2, const float* __restrict__ b2,
    float* __restrict__ out)
{
    int t = threadIdx.x;
    int grp = t >> 4, cc = t & 15;
    int n = blockIdx.x * 16 + grp;     // NN/16 = 6250 exact
    float cs = att_s2[0];
    float gdcd = g[n] * att_d2[0];
    int beg = rowptr[n], end = rowptr[n + 1];
    float acc = 0.f, den = 0.f;
    for (int j = beg + cc; j < end; j += 16) {
        float gz = g[csr[j]];
        float a = gz * cs + gdcd;
        a = a > 0.f ? a : NEG * a;
        float ev = __expf(a);
        den += ev;
        acc += ev * gz;
    }
#pragma unroll
    for (int m = 1; m <= 8; m <<= 1) {
        acc += __shfl_xor(acc, m);
        den += __shfl_xor(den, m);
    }
    if (cc == 0) out[n] = acc / (den + EPSV) + b2[0];
}

extern "C" void kernel_launch(void* const* d_in, const int* in_sizes, int n_in,
                              void* d_out, int out_size, void* d_ws, size_t ws_size,
                              hipStream_t stream)
{
    const float* x   = (const float*)d_in[0];
    const int*   ei  = (const int*)d_in[1];
    const float* W1  = (const float*)d_in[2];
    const float* as1 = (const float*)d_in[3];
    const float* ad1 = (const float*)d_in[4];
    const float* b1  = (const float*)d_in[5];
    const float* W2  = (const float*)d_in[6];
    const float* as2 = (const float*)d_in[7];
    const float* ad2 = (const float*)d_in[8];
    const float* b2  = (const float*)d_in[9];
    float* out = (float*)d_out;

    // workspace layout (4-byte units, 128-slot aligned blocks)
    int*   iw      = (int*)d_ws;
    float* fw      = (float*)d_ws;
    int*   bcnt    = iw;                  //      391
    int*   bbase   = iw + 512;            //      391
    int*   bcursor = iw + 1024;           //      391
    int*   rowptr  = iw + 1536;           //  100,001
    int*   bin     = iw + 101632;         // 1,700,000
    int*   csr     = iw + 1801728;        // 1,700,000
    float* adst1   = fw + 3501824;        //   400,000
    float* asrc1   = fw + 3901952;        //   400,000
    float* g       = fw + 4302080;        //   100,000
    __half* h1h    = (__half*)(fw + 4402176); // 6.4M halves
    // total ≈ 7.6M slots ≈ 30.4 MB

    hipMemsetAsync(bcnt, 0, NB * sizeof(int), stream);

    k_bcount<<<NBLK4, BS, 0, stream>>>(ei, bcnt);
    k_bscan <<<1, 512, 0, stream>>>(bcnt, bbase, bcursor, rowptr);
    k_bscat <<<NBLK4, BS, 0, stream>>>(ei, bcursor, bin);
    k_bcsr  <<<NB, 256, 0, stream>>>(bin, bbase, bcnt, rowptr, csr);
    k_gemm1 <<<(NN / 32 + 3) / 4, 256, 0, stream>>>(x, W1, as1, ad1, h1h, asrc1, adst1);
    k_e1agg <<<(NN * 4 + 255) / 256, 256, 0, stream>>>(rowptr, csr, asrc1, adst1, h1h, b1, W2, g);
    k_e2agg <<<NN / 16, 256, 0, stream>>>(rowptr, csr, g, as2, ad2, b2, out);
}